// Round 2
// baseline (481.983 us; speedup 1.0000x reference)
//
#include <hip/hip_runtime.h>
#include <stdint.h>
#include <math.h>

// PendulumHJBLoss: 3 MLP passes (2->128->128->2, tanh) over N=524288 + losses.
// R1: per-lane direct layer-1 (no shfl / no LDS h1 / no in-loop barriers),
// v_perm bf16 packing, enc passes fused into one dispatch, elementwise loss
// fused into decoder epilogue, v_cos instead of libm cosf.
// Symplectic FD term stays exact fp32 (EPS=1e-4 can't survive bf16).

constexpr float EPS_FD = 1e-4f;
constexpr int NBLK_MLP = 1024;

typedef float f32x4 __attribute__((ext_vector_type(4)));
typedef short s16x8 __attribute__((ext_vector_type(8)));

__device__ __forceinline__ float tanh_fast(float x) {
  // tanh(x) = 1 - 2/(e^{2x}+1); exp2/rcp single HW instrs.
  float e = __builtin_amdgcn_exp2f(x * 2.8853900817779268f); // 2*log2(e)
  return 1.0f - 2.0f * __builtin_amdgcn_rcpf(e + 1.0f);
}
__device__ __forceinline__ float cos_fast(float x) {
  // v_cos_f32 takes revolutions, does its own range reduction.
  return __builtin_amdgcn_cosf(x * 0.15915494309189535f);
}
__device__ __forceinline__ unsigned bf16rne(float f) {
  union { float f; unsigned u; } v; v.f = f;
  return (v.u + 0x7FFFu + ((v.u >> 16) & 1u)) >> 16;
}
__device__ __forceinline__ unsigned pack2rne(float a, float b) {
  return bf16rne(a) | (bf16rne(b) << 16);
}
// pack two fp32 -> bf16 pair (round-half-up) with one v_perm
__device__ __forceinline__ unsigned packbf(float lo, float hi) {
  union { float f; unsigned u; } a, b; a.f = lo; b.f = hi;
  return __builtin_amdgcn_perm(b.u + 0x8000u, a.u + 0x8000u, 0x07060302u);
}

// ---------------------------------------------------------------------------
// Pre-swizzle W2 (fp32 [128][128]) into MFMA B-frag order, bf16.
// Frag f = s*8+t. Lane L holds B[k=32s+(L>>4)*8+j][col=16t+(L&15)], j=0..7.
// enc at frag[0..8191], dec at frag[8192..16383].
// ---------------------------------------------------------------------------
__global__ void prep_w2(const float* __restrict__ encW2,
                        const float* __restrict__ decW2,
                        unsigned* __restrict__ frag) {
  int id = blockIdx.x * blockDim.x + threadIdx.x;  // 0..16383
  const float* W = (id < 8192) ? encW2 : decW2;
  int l = id & 8191;
  int jj   = l & 3;
  int lane = (l >> 2) & 63;
  int f    = l >> 8;            // 0..31
  int s = f >> 3, t = f & 7;
  int quad = lane >> 4, nn = lane & 15;
  int k   = 32 * s + quad * 8 + 2 * jj;
  int col = 16 * t + nn;
  frag[id] = pack2rne(W[k * 128 + col], W[(k + 1) * 128 + col]);
}

// ---------------------------------------------------------------------------
// MLP pass. DUAL: grid covers 2*ntiles, second half uses xpB/xqB -> oPB/oQB.
// LOSS: no stores; fuse elementwise loss terms, per-block partial sums.
// Per wave: one 16-element tile per grid-stride step. No in-loop barriers.
// ---------------------------------------------------------------------------
template<bool DUAL, bool LOSS>
__global__ __launch_bounds__(256, 2) void mlp_fused(
    const float* __restrict__ xpA, const float* __restrict__ xqA,
    const float* __restrict__ xpB, const float* __restrict__ xqB,
    const uint4* __restrict__ w2frag,
    const float* __restrict__ W1, const float* __restrict__ b1,
    const float* __restrict__ b2, const float* __restrict__ W3,
    const float* __restrict__ b3,
    float* __restrict__ oPA, float* __restrict__ oQA,
    float* __restrict__ oPB, float* __restrict__ oQB,
    const float* __restrict__ lp0, const float* __restrict__ lq0,
    const float* __restrict__ lP1, const float* __restrict__ lQ1,
    const float* __restrict__ lom, const float* __restrict__ lPt,
    const float* __restrict__ lQt, const float* __restrict__ ldt,
    float* __restrict__ partials, int n)
{
  __shared__ uint4 Bf[2048];                 // 32 KB: all 32 B-frags
  __shared__ float red[4][5];

  int tid = threadIdx.x;
  for (int i = tid; i < 2048; i += 256) Bf[i] = w2frag[i];

  int wave = tid >> 6, lane = tid & 63;
  int quad = lane >> 4, l15 = lane & 15;

  // per-lane layer-1 constants: k-set = {32s + quad*8 + j : s=0..3, j=0..7}
  float w0k[32], w1k[32], bk[32];
#pragma unroll
  for (int s = 0; s < 4; s++) {
    int k = 32 * s + quad * 8;
    float4 a0 = *(const float4*)(W1 + k);
    float4 a1 = *(const float4*)(W1 + k + 4);
    float4 c0 = *(const float4*)(W1 + 128 + k);
    float4 c1 = *(const float4*)(W1 + 128 + k + 4);
    float4 d0 = *(const float4*)(b1 + k);
    float4 d1 = *(const float4*)(b1 + k + 4);
    w0k[8*s+0]=a0.x; w0k[8*s+1]=a0.y; w0k[8*s+2]=a0.z; w0k[8*s+3]=a0.w;
    w0k[8*s+4]=a1.x; w0k[8*s+5]=a1.y; w0k[8*s+6]=a1.z; w0k[8*s+7]=a1.w;
    w1k[8*s+0]=c0.x; w1k[8*s+1]=c0.y; w1k[8*s+2]=c0.z; w1k[8*s+3]=c0.w;
    w1k[8*s+4]=c1.x; w1k[8*s+5]=c1.y; w1k[8*s+6]=c1.z; w1k[8*s+7]=c1.w;
    bk[8*s+0]=d0.x; bk[8*s+1]=d0.y; bk[8*s+2]=d0.z; bk[8*s+3]=d0.w;
    bk[8*s+4]=d1.x; bk[8*s+5]=d1.y; bk[8*s+6]=d1.z; bk[8*s+7]=d1.w;
  }
  float b2v[8], w3P[8], w3Q[8];
#pragma unroll
  for (int t = 0; t < 8; t++) {
    b2v[t] = b2[16 * t + l15];
    w3P[t] = W3[(16 * t + l15) * 2];
    w3Q[t] = W3[(16 * t + l15) * 2 + 1];
  }
  float b3P = b3[0], b3Q = b3[1];
  float dt = 0.f;
  if constexpr (LOSS) dt = ldt[0];
  float s0 = 0.f, s1 = 0.f, s2 = 0.f, s3 = 0.f, s4 = 0.f;
  __syncthreads();   // Bf ready; only barrier before the loop

  int nwaves = gridDim.x * 4;
  int gwave  = blockIdx.x * 4 + wave;
  int ntiles = (n + 15) >> 4;
  int ttot   = DUAL ? 2 * ntiles : ntiles;

  for (int tile = gwave; tile < ttot; tile += nwaves) {
    bool second = DUAL && (tile >= ntiles);
    int t0 = second ? tile - ntiles : tile;
    int base = t0 * 16;
    const float* xp = (DUAL && second) ? xpB : xpA;
    const float* xq = (DUAL && second) ? xqB : xqA;
    int e = base + l15; if (e >= n) e = n - 1;
    float pe = xp[e], qe = xq[e];

    // layer 1 directly in A-frag layout: lane holds elem l15, dims quad*8+j+32s
    unsigned uA[16];
#pragma unroll
    for (int s = 0; s < 4; s++) {
#pragma unroll
      for (int jj = 0; jj < 4; jj++) {
        int k = 8 * s + 2 * jj;
        float a0 = tanh_fast(fmaf(pe, w0k[k],   fmaf(qe, w1k[k],   bk[k])));
        float a1 = tanh_fast(fmaf(pe, w0k[k+1], fmaf(qe, w1k[k+1], bk[k+1])));
        uA[4 * s + jj] = packbf(a0, a1);
      }
    }

    f32x4 acc[8];
#pragma unroll
    for (int t = 0; t < 8; t++) {
      f32x4 z = {b2v[t], b2v[t], b2v[t], b2v[t]};   // fold b2 into accumulator
      acc[t] = z;
    }
#pragma unroll
    for (int s = 0; s < 4; s++) {
      uint4 au = {uA[4*s], uA[4*s+1], uA[4*s+2], uA[4*s+3]};
      s16x8 Av = *reinterpret_cast<s16x8*>(&au);
#pragma unroll
      for (int t = 0; t < 8; t++) {
        uint4 bu = Bf[(s * 8 + t) * 64 + lane];
        s16x8 Bv = *reinterpret_cast<s16x8*>(&bu);
        acc[t] = __builtin_amdgcn_mfma_f32_16x16x32_bf16(Av, Bv, acc[t], 0, 0, 0);
      }
    }

    // epilogue: acc[t][r] = h2 pre-act of elem (quad*4+r), col (16t+l15)
    float sP[4] = {0, 0, 0, 0}, sQ[4] = {0, 0, 0, 0};
#pragma unroll
    for (int t = 0; t < 8; t++) {
#pragma unroll
      for (int r = 0; r < 4; r++) {
        float h = tanh_fast(acc[t][r]);
        sP[r] = fmaf(h, w3P[t], sP[r]);
        sQ[r] = fmaf(h, w3Q[t], sQ[r]);
      }
    }
#pragma unroll
    for (int m = 1; m < 16; m <<= 1) {
#pragma unroll
      for (int r = 0; r < 4; r++) {
        sP[r] += __shfl_xor(sP[r], m, 64);
        sQ[r] += __shfl_xor(sQ[r], m, 64);
      }
    }
    if (l15 < 4) {
      int rr = l15;
      float vP = (rr == 0) ? sP[0] : (rr == 1) ? sP[1] : (rr == 2) ? sP[2] : sP[3];
      float vQ = (rr == 0) ? sQ[0] : (rr == 1) ? sQ[1] : (rr == 2) ? sQ[2] : sQ[3];
      vP += b3P; vQ += b3Q;
      int o = base + quad * 4 + l15;
      if (o < n) {
        if constexpr (!LOSS) {
          float* oP = (DUAL && second) ? oPB : oPA;
          float* oQ = (DUAL && second) ? oQB : oQA;
          oP[o] = vP; oQ[o] = vQ;
        } else {
          // vP,vQ = p0_recon,q0_recon; xpA,xqA = P0,Q0 arrays
          float dp = lp0[o] - vP, dq = lq0[o] - vQ;
          s0 += dp * dp + dq * dq;
          float P0o = xpA[o], Q0o = xqA[o];
          float d1 = P0o - lP1[o]; s1 += d1 * d1;
          s2 += 1.0f - cos_fast(lQ1[o] - Q0o - lom[o] * dt);
          float g = P0o - lPt[o]; s3 += g * g;
          s4 += 1.0f - cos_fast(Q0o - lQt[o]);
        }
      }
    }
  }

  if constexpr (LOSS) {
#pragma unroll
    for (int m = 1; m < 64; m <<= 1) {
      s0 += __shfl_xor(s0, m, 64);
      s1 += __shfl_xor(s1, m, 64);
      s2 += __shfl_xor(s2, m, 64);
      s3 += __shfl_xor(s3, m, 64);
      s4 += __shfl_xor(s4, m, 64);
    }
    if (lane == 0) {
      red[wave][0] = s0; red[wave][1] = s1; red[wave][2] = s2;
      red[wave][3] = s3; red[wave][4] = s4;
    }
    __syncthreads();
    if (tid < 5) {
      partials[blockIdx.x * 8 + tid] =
          red[0][tid] + red[1][tid] + red[2][tid] + red[3][tid];
    }
  }
}

// ---------------------------------------------------------------------------
// Exact fp32 encode of the 128 perturbed symplectic rows (block = one row).
// ---------------------------------------------------------------------------
__global__ void symp_encode(const float* __restrict__ p0, const float* __restrict__ q0,
                            const float* __restrict__ W1, const float* __restrict__ b1,
                            const float* __restrict__ W2, const float* __restrict__ b2,
                            const float* __restrict__ W3, const float* __restrict__ b3,
                            float* __restrict__ PQ)
{
  int b = blockIdx.x;   // 0..127
  int t = threadIdx.x;  // 0..127
  int m = b & 31, c = b >> 5;   // c: 0=p+e 1=p-e 2=q+e 3=q-e
  float p = p0[m], q = q0[m];
  if (c == 0) p += EPS_FD; else if (c == 1) p -= EPS_FD;
  else if (c == 2) q += EPS_FD; else q -= EPS_FD;

  __shared__ float h1[128], h2[128];
  h1[t] = tanhf(fmaf(p, W1[t], fmaf(q, W1[128 + t], b1[t])));
  __syncthreads();
  float a = b2[t];
  for (int k = 0; k < 128; k++) a = fmaf(h1[k], W2[k * 128 + t], a);
  h2[t] = tanhf(a);
  __syncthreads();
  float cP = h2[t] * W3[2 * t];
  float cQ = h2[t] * W3[2 * t + 1];
#pragma unroll
  for (int mm = 1; mm < 64; mm <<= 1) {
    cP += __shfl_xor(cP, mm, 64);
    cQ += __shfl_xor(cQ, mm, 64);
  }
  __shared__ float rr[2][2];
  if ((t & 63) == 0) { rr[t >> 6][0] = cP; rr[t >> 6][1] = cQ; }
  __syncthreads();
  if (t == 0) {
    PQ[2 * b]     = rr[0][0] + rr[1][0] + b3[0];
    PQ[2 * b + 1] = rr[0][1] + rr[1][1] + b3[1];
  }
}

// ---------------------------------------------------------------------------
// Sum loss partials + finite differences + Poisson bracket -> d_out[6]
// ---------------------------------------------------------------------------
__global__ void finalize(const float* __restrict__ partials, int nblk,
                         const float* __restrict__ PQ,
                         float* __restrict__ out, int n)
{
  int t = threadIdx.x;  // 64 threads, 1 wave
  float v = 0.f;
  if (t < 32) {
    float Ppp = PQ[2 * t],            Qpp = PQ[2 * t + 1];
    float Ppm = PQ[2 * (32 + t)],     Qpm = PQ[2 * (32 + t) + 1];
    float Pqp = PQ[2 * (64 + t)],     Qqp = PQ[2 * (64 + t) + 1];
    float Pqm = PQ[2 * (96 + t)],     Qqm = PQ[2 * (96 + t) + 1];
    float inv2e = 1.0f / (2.0f * EPS_FD);
    float dPdp = (Ppp - Ppm) * inv2e, dPdq = (Pqp - Pqm) * inv2e;
    float dQdp = (Qpp - Qpm) * inv2e, dQdq = (Qqp - Qqm) * inv2e;
    float pb = dPdq * dQdp - dPdp * dQdq;
    float d = fabsf(pb) - 1.0f;
    v = d * d;
  }
#pragma unroll
  for (int m = 1; m < 64; m <<= 1) v += __shfl_xor(v, m, 64);

  float sums[5];
  for (int i = 0; i < 5; i++) {
    float a = 0.f;
    for (int j = t; j < nblk; j += 64) a += partials[j * 8 + i];
#pragma unroll
    for (int m = 1; m < 64; m <<= 1) a += __shfl_xor(a, m, 64);
    sums[i] = a;
  }
  if (t == 0) {
    float inv_n = 1.0f / (float)n;
    float recon = sums[0] * inv_n;
    float cons  = sums[1] * inv_n;
    float evo   = sums[2] * inv_n;
    float gauge = (sums[3] + sums[4]) * inv_n;
    float symp  = v * (1.0f / 32.0f);
    float total = recon + 10.0f * cons + 5.0f * evo + 0.1f * symp + 5.0f * gauge;
    out[0] = total; out[1] = recon; out[2] = cons;
    out[3] = evo;   out[4] = symp;  out[5] = gauge;
  }
}

extern "C" void kernel_launch(void* const* d_in, const int* in_sizes, int n_in,
                              void* d_out, int out_size, void* d_ws, size_t ws_size,
                              hipStream_t stream)
{
  const float* p0    = (const float*)d_in[0];
  const float* q0    = (const float*)d_in[1];
  const float* p1    = (const float*)d_in[2];
  const float* q1    = (const float*)d_in[3];
  const float* omega = (const float*)d_in[4];
  const float* dtp   = (const float*)d_in[5];
  const float* Pt    = (const float*)d_in[6];
  const float* Qt    = (const float*)d_in[7];
  const float* encW1 = (const float*)d_in[8];
  const float* encb1 = (const float*)d_in[9];
  const float* encW2 = (const float*)d_in[10];
  const float* encb2 = (const float*)d_in[11];
  const float* encW3 = (const float*)d_in[12];
  const float* encb3 = (const float*)d_in[13];
  const float* decW1 = (const float*)d_in[14];
  const float* decb1 = (const float*)d_in[15];
  const float* decW2 = (const float*)d_in[16];
  const float* decb2 = (const float*)d_in[17];
  const float* decW3 = (const float*)d_in[18];
  const float* decb3 = (const float*)d_in[19];

  int n = in_sizes[0];
  char* ws = (char*)d_ws;
  unsigned* frag = (unsigned*)ws;              // 16384 u32 = 64 KB
  float* P0 = (float*)(ws + 65536);
  float* Q0 = P0 + n;
  float* P1 = Q0 + n;
  float* Q1 = P1 + n;
  float* PQ = Q1 + n;                          // 256 floats
  float* partials = PQ + 256;                  // NBLK_MLP*8 floats

  prep_w2<<<64, 256, 0, stream>>>(encW2, decW2, frag);

  mlp_fused<true, false><<<NBLK_MLP, 256, 0, stream>>>(
      p0, q0, p1, q1, (const uint4*)frag,
      encW1, encb1, encb2, encW3, encb3,
      P0, Q0, P1, Q1,
      nullptr, nullptr, nullptr, nullptr, nullptr, nullptr, nullptr, nullptr,
      nullptr, n);

  symp_encode<<<128, 128, 0, stream>>>(p0, q0, encW1, encb1, encW2, encb2,
                                       encW3, encb3, PQ);

  mlp_fused<false, true><<<NBLK_MLP, 256, 0, stream>>>(
      P0, Q0, nullptr, nullptr, (const uint4*)(frag + 8192),
      decW1, decb1, decb2, decW3, decb3,
      nullptr, nullptr, nullptr, nullptr,
      p0, q0, P1, Q1, omega, Pt, Qt, dtp,
      partials, n);

  finalize<<<1, 64, 0, stream>>>(partials, NBLK_MLP, PQ, (float*)d_out, n);
}

// Round 3
// 359.859 us; speedup vs baseline: 1.3394x; 1.3394x over previous
//
#include <hip/hip_runtime.h>
#include <stdint.h>
#include <math.h>

// PendulumHJBLoss: 3 MLP passes (2->128->128->2, tanh) over N=524288 + losses.
// R3: R0's low-register layer-1 (shfl broadcast + wave-private LDS h1, NO
// in-loop barriers -- same-wave LDS ops are in-order), v_perm bf16 pack,
// b2 folded into MFMA acc, dual-encoder dispatch, loss fused into decoder
// epilogue, finalize folded into last decoder block (ticket counter).
// Symplectic FD term exact fp32 (EPS=1e-4 cannot survive bf16).

constexpr float EPS_FD = 1e-4f;
constexpr int NBLK_MLP = 1024;

typedef float f32x4 __attribute__((ext_vector_type(4)));
typedef short s16x8 __attribute__((ext_vector_type(8)));

__device__ __forceinline__ float tanh_fast(float x) {
  // tanh(x) = 1 - 2/(e^{2x}+1); exp2/rcp single HW instrs.
  float e = __builtin_amdgcn_exp2f(x * 2.8853900817779268f); // 2*log2(e)
  return 1.0f - 2.0f * __builtin_amdgcn_rcpf(e + 1.0f);
}
__device__ __forceinline__ float cos_fast(float x) {
  // v_cos_f32 takes revolutions, own range reduction.
  return __builtin_amdgcn_cosf(x * 0.15915494309189535f);
}
__device__ __forceinline__ unsigned bf16rne(float f) {
  union { float f; unsigned u; } v; v.f = f;
  return (v.u + 0x7FFFu + ((v.u >> 16) & 1u)) >> 16;
}
__device__ __forceinline__ unsigned pack2rne(float a, float b) {
  return bf16rne(a) | (bf16rne(b) << 16);
}
// pack two fp32 -> bf16 pair (round-half-up) with one v_perm
__device__ __forceinline__ unsigned packbf(float lo, float hi) {
  union { float f; unsigned u; } a, b; a.f = lo; b.f = hi;
  return __builtin_amdgcn_perm(b.u + 0x8000u, a.u + 0x8000u, 0x07060302u);
}

// ---------------------------------------------------------------------------
// Setup: blocks 0-63 swizzle W2 -> MFMA B-frags (bf16); blocks 64-127 compute
// the 128 perturbed symplectic encodes in exact fp32 (2 rows per block).
// Block 0 also zero-inits the loss accumulators + ticket counter.
// ---------------------------------------------------------------------------
__global__ void setup_kernel(const float* __restrict__ encW2,
                             const float* __restrict__ decW2,
                             unsigned* __restrict__ frag,
                             const float* __restrict__ p0, const float* __restrict__ q0,
                             const float* __restrict__ W1, const float* __restrict__ b1,
                             const float* __restrict__ W2, const float* __restrict__ b2,
                             const float* __restrict__ W3, const float* __restrict__ b3,
                             float* __restrict__ PQ,
                             float* __restrict__ acc5, unsigned* __restrict__ counter)
{
  int tid = threadIdx.x;
  if (blockIdx.x < 64) {
    if (blockIdx.x == 0 && tid < 6) {
      if (tid < 5) acc5[tid] = 0.f; else *counter = 0u;
    }
    // W2 swizzle: frag f=s*8+t; lane L holds B[k=32s+(L>>4)*8+j][col=16t+(L&15)]
    int id = blockIdx.x * 256 + tid;            // 0..16383
    const float* W = (id < 8192) ? encW2 : decW2;
    int l = id & 8191;
    int jj   = l & 3;
    int lane = (l >> 2) & 63;
    int f    = l >> 8;
    int s = f >> 3, t = f & 7;
    int quad = lane >> 4, nn = lane & 15;
    int k   = 32 * s + quad * 8 + 2 * jj;
    int col = 16 * t + nn;
    frag[id] = pack2rne(W[k * 128 + col], W[(k + 1) * 128 + col]);
  } else {
    // symplectic rows: row = (blk-64)*2 + (tid>>7); c: 0=p+e 1=p-e 2=q+e 3=q-e
    int half = tid >> 7;
    int tt   = tid & 127;
    int row  = (blockIdx.x - 64) * 2 + half;
    int m = row & 31, c = row >> 5;
    float p = p0[m], q = q0[m];
    if (c == 0) p += EPS_FD; else if (c == 1) p -= EPS_FD;
    else if (c == 2) q += EPS_FD; else q -= EPS_FD;

    __shared__ float h1[2][128];
    h1[half][tt] = tanhf(fmaf(p, W1[tt], fmaf(q, W1[128 + tt], b1[tt])));
    __syncthreads();
    float a = b2[tt];
    for (int k = 0; k < 128; k++) a = fmaf(h1[half][k], W2[k * 128 + tt], a);
    float hh = tanhf(a);
    float cP = hh * W3[2 * tt];
    float cQ = hh * W3[2 * tt + 1];
#pragma unroll
    for (int mm = 1; mm < 64; mm <<= 1) {
      cP += __shfl_xor(cP, mm, 64);
      cQ += __shfl_xor(cQ, mm, 64);
    }
    __shared__ float rr[4][2];
    int wv = tid >> 6, ln = tid & 63;
    if (ln == 0) { rr[wv][0] = cP; rr[wv][1] = cQ; }
    __syncthreads();
    if (tt == 0) {
      PQ[2 * row]     = rr[2 * half][0] + rr[2 * half + 1][0] + b3[0];
      PQ[2 * row + 1] = rr[2 * half][1] + rr[2 * half + 1][1] + b3[1];
    }
  }
}

// ---------------------------------------------------------------------------
// MLP pass. DUAL: grid covers 2*ntiles (xpB/xqB -> oPB/oQB for second half).
// LOSS: fuse elementwise loss; last finishing block computes d_out[6].
// Per wave: one 16-elem tile per step. Wave-private h1 staging, no barriers.
// ---------------------------------------------------------------------------
template<bool DUAL, bool LOSS>
__global__ void mlp_fused(
    const float* __restrict__ xpA, const float* __restrict__ xqA,
    const float* __restrict__ xpB, const float* __restrict__ xqB,
    const uint4* __restrict__ w2frag,
    const float* __restrict__ W1, const float* __restrict__ b1,
    const float* __restrict__ b2, const float* __restrict__ W3,
    const float* __restrict__ b3,
    float* __restrict__ oPA, float* __restrict__ oQA,
    float* __restrict__ oPB, float* __restrict__ oQB,
    const float* __restrict__ lp0, const float* __restrict__ lq0,
    const float* __restrict__ lP1, const float* __restrict__ lQ1,
    const float* __restrict__ lom, const float* __restrict__ lPt,
    const float* __restrict__ lQt, const float* __restrict__ ldt,
    float* __restrict__ acc5, unsigned* __restrict__ counter,
    const float* __restrict__ PQ, float* __restrict__ out, int n)
{
  __shared__ uint4 Bf[2048];                 // 32 KB: all 32 B-frags
  __shared__ unsigned h1s[4][16 * 68 + 4];   // wave-private h1 staging
  __shared__ float red[4][5];
  __shared__ unsigned lastflag;

  int tid = threadIdx.x;
  for (int i = tid; i < 2048; i += 256) Bf[i] = w2frag[i];

  int wave = tid >> 6, lane = tid & 63;
  int quad = lane >> 4, l15 = lane & 15;

  // layer-1 consts: lane owns hidden dims 2*lane, 2*lane+1 (6 regs total)
  float w10_0 = W1[2 * lane],       w10_1 = W1[2 * lane + 1];
  float w11_0 = W1[128 + 2 * lane], w11_1 = W1[128 + 2 * lane + 1];
  float b1_0 = b1[2 * lane], b1_1 = b1[2 * lane + 1];
  float b2v[8], w3P[8], w3Q[8];
#pragma unroll
  for (int t = 0; t < 8; t++) {
    b2v[t] = b2[16 * t + l15];
    w3P[t] = W3[(16 * t + l15) * 2];
    w3Q[t] = W3[(16 * t + l15) * 2 + 1];
  }
  float b3P = b3[0], b3Q = b3[1];
  float dt = 0.f;
  if constexpr (LOSS) dt = ldt[0];
  float s0 = 0.f, s1 = 0.f, s2 = 0.f, s3 = 0.f, s4 = 0.f;
  __syncthreads();   // Bf ready; the ONLY barrier before the tail

  int nwaves = gridDim.x * 4;
  int gwave  = blockIdx.x * 4 + wave;
  int ntiles = (n + 15) >> 4;
  int ttot   = DUAL ? 2 * ntiles : ntiles;
  unsigned* hrow = &h1s[wave][0];

  for (int tile = gwave; tile < ttot; tile += nwaves) {
    bool second = DUAL && (tile >= ntiles);
    int base = (second ? tile - ntiles : tile) * 16;
    const float* xp = (DUAL && second) ? xpB : xpA;
    const float* xq = (DUAL && second) ? xqB : xqA;
    int e = base + l15; if (e >= n) e = n - 1;
    float pe = xp[e], qe = xq[e];

    // layer 1: lane computes h1[e][2*lane..2*lane+1] for e=0..15
#pragma unroll
    for (int ee = 0; ee < 16; ee++) {
      float p = __shfl(pe, ee, 64);
      float q = __shfl(qe, ee, 64);
      float a0 = tanh_fast(fmaf(p, w10_0, fmaf(q, w11_0, b1_0)));
      float a1 = tanh_fast(fmaf(p, w10_1, fmaf(q, w11_1, b1_1)));
      hrow[ee * 68 + lane] = packbf(a0, a1);
    }
    __builtin_amdgcn_wave_barrier();  // compiler fence; same-wave LDS is in-order

    // A-frags: lane holds h1[elem=l15][k=32s+quad*8+j]
    s16x8 A[4];
#pragma unroll
    for (int s = 0; s < 4; s++) {
      uint4 u = *reinterpret_cast<const uint4*>(&hrow[l15 * 68 + 16 * s + 4 * quad]);
      A[s] = *reinterpret_cast<s16x8*>(&u);
    }
    __builtin_amdgcn_wave_barrier();  // keep reads before next iter's writes

    f32x4 acc[8];
#pragma unroll
    for (int t = 0; t < 8; t++) {
      f32x4 z = {b2v[t], b2v[t], b2v[t], b2v[t]};   // b2 folded into acc
      acc[t] = z;
    }
#pragma unroll
    for (int s = 0; s < 4; s++) {
#pragma unroll
      for (int t = 0; t < 8; t++) {
        uint4 bu = Bf[(s * 8 + t) * 64 + lane];
        s16x8 Bv = *reinterpret_cast<s16x8*>(&bu);
        acc[t] = __builtin_amdgcn_mfma_f32_16x16x32_bf16(A[s], Bv, acc[t], 0, 0, 0);
      }
    }

    // epilogue: acc[t][r] = h2 pre-act of elem (quad*4+r), col (16t+l15)
    float sP[4] = {0, 0, 0, 0}, sQ[4] = {0, 0, 0, 0};
#pragma unroll
    for (int t = 0; t < 8; t++) {
#pragma unroll
      for (int r = 0; r < 4; r++) {
        float h = tanh_fast(acc[t][r]);
        sP[r] = fmaf(h, w3P[t], sP[r]);
        sQ[r] = fmaf(h, w3Q[t], sQ[r]);
      }
    }
#pragma unroll
    for (int m = 1; m < 16; m <<= 1) {
#pragma unroll
      for (int r = 0; r < 4; r++) {
        sP[r] += __shfl_xor(sP[r], m, 64);
        sQ[r] += __shfl_xor(sQ[r], m, 64);
      }
    }
    if (l15 < 4) {
      float vP = (l15 == 0) ? sP[0] : (l15 == 1) ? sP[1] : (l15 == 2) ? sP[2] : sP[3];
      float vQ = (l15 == 0) ? sQ[0] : (l15 == 1) ? sQ[1] : (l15 == 2) ? sQ[2] : sQ[3];
      vP += b3P; vQ += b3Q;
      int o = base + quad * 4 + l15;
      if (o < n) {
        if constexpr (!LOSS) {
          float* oP = (DUAL && second) ? oPB : oPA;
          float* oQ = (DUAL && second) ? oQB : oQA;
          oP[o] = vP; oQ[o] = vQ;
        } else {
          // vP,vQ = p0_recon,q0_recon; xpA,xqA = P0,Q0 arrays
          float dp = lp0[o] - vP, dq = lq0[o] - vQ;
          s0 += dp * dp + dq * dq;
          float P0o = xpA[o], Q0o = xqA[o];
          float d1 = P0o - lP1[o]; s1 += d1 * d1;
          s2 += 1.0f - cos_fast(lQ1[o] - Q0o - lom[o] * dt);
          float g = P0o - lPt[o]; s3 += g * g;
          s4 += 1.0f - cos_fast(Q0o - lQt[o]);
        }
      }
    }
  }

  if constexpr (LOSS) {
#pragma unroll
    for (int m = 1; m < 64; m <<= 1) {
      s0 += __shfl_xor(s0, m, 64);
      s1 += __shfl_xor(s1, m, 64);
      s2 += __shfl_xor(s2, m, 64);
      s3 += __shfl_xor(s3, m, 64);
      s4 += __shfl_xor(s4, m, 64);
    }
    if (lane == 0) {
      red[wave][0] = s0; red[wave][1] = s1; red[wave][2] = s2;
      red[wave][3] = s3; red[wave][4] = s4;
    }
    __syncthreads();
    if (tid == 0) {
      // single thread: adds -> fence -> ticket (ordering is single-thread)
#pragma unroll
      for (int i = 0; i < 5; i++)
        atomicAdd(&acc5[i], red[0][i] + red[1][i] + red[2][i] + red[3][i]);
      __threadfence();
      unsigned prev = atomicAdd(counter, 1u);
      lastflag = (prev == gridDim.x - 1) ? 1u : 0u;
    }
    __syncthreads();
    if (lastflag) {
      __threadfence();
      if (tid < 64) {
        float v = 0.f;
        if (tid < 32) {
          float Ppp = PQ[2 * tid],          Qpp = PQ[2 * tid + 1];
          float Ppm = PQ[2 * (32 + tid)],   Qpm = PQ[2 * (32 + tid) + 1];
          float Pqp = PQ[2 * (64 + tid)],   Qqp = PQ[2 * (64 + tid) + 1];
          float Pqm = PQ[2 * (96 + tid)],   Qqm = PQ[2 * (96 + tid) + 1];
          float inv2e = 1.0f / (2.0f * EPS_FD);
          float dPdp = (Ppp - Ppm) * inv2e, dPdq = (Pqp - Pqm) * inv2e;
          float dQdp = (Qpp - Qpm) * inv2e, dQdq = (Qqp - Qqm) * inv2e;
          float pb = dPdq * dQdp - dPdp * dQdq;
          float d = fabsf(pb) - 1.0f;
          v = d * d;
        }
#pragma unroll
        for (int m = 1; m < 64; m <<= 1) v += __shfl_xor(v, m, 64);
        if (tid == 0) {
          float inv_n = 1.0f / (float)n;
          float recon = atomicAdd(&acc5[0], 0.f) * inv_n;
          float cons  = atomicAdd(&acc5[1], 0.f) * inv_n;
          float evo   = atomicAdd(&acc5[2], 0.f) * inv_n;
          float gauge = (atomicAdd(&acc5[3], 0.f) + atomicAdd(&acc5[4], 0.f)) * inv_n;
          float symp  = v * (1.0f / 32.0f);
          float total = recon + 10.0f * cons + 5.0f * evo + 0.1f * symp + 5.0f * gauge;
          out[0] = total; out[1] = recon; out[2] = cons;
          out[3] = evo;   out[4] = symp;  out[5] = gauge;
        }
      }
    }
  }
}

extern "C" void kernel_launch(void* const* d_in, const int* in_sizes, int n_in,
                              void* d_out, int out_size, void* d_ws, size_t ws_size,
                              hipStream_t stream)
{
  const float* p0    = (const float*)d_in[0];
  const float* q0    = (const float*)d_in[1];
  const float* p1    = (const float*)d_in[2];
  const float* q1    = (const float*)d_in[3];
  const float* omega = (const float*)d_in[4];
  const float* dtp   = (const float*)d_in[5];
  const float* Pt    = (const float*)d_in[6];
  const float* Qt    = (const float*)d_in[7];
  const float* encW1 = (const float*)d_in[8];
  const float* encb1 = (const float*)d_in[9];
  const float* encW2 = (const float*)d_in[10];
  const float* encb2 = (const float*)d_in[11];
  const float* encW3 = (const float*)d_in[12];
  const float* encb3 = (const float*)d_in[13];
  const float* decW1 = (const float*)d_in[14];
  const float* decb1 = (const float*)d_in[15];
  const float* decW2 = (const float*)d_in[16];
  const float* decb2 = (const float*)d_in[17];
  const float* decW3 = (const float*)d_in[18];
  const float* decb3 = (const float*)d_in[19];

  int n = in_sizes[0];
  char* ws = (char*)d_ws;
  unsigned* frag = (unsigned*)ws;              // 16384 u32 = 64 KB
  float* P0 = (float*)(ws + 65536);
  float* Q0 = P0 + n;
  float* P1 = Q0 + n;
  float* Q1 = P1 + n;
  float* PQ = Q1 + n;                          // 256 floats
  float* acc5 = PQ + 256;                      // 5 accumulators
  unsigned* counter = (unsigned*)(acc5 + 8);   // ticket

  setup_kernel<<<128, 256, 0, stream>>>(encW2, decW2, frag,
                                        p0, q0, encW1, encb1, encW2, encb2,
                                        encW3, encb3, PQ, acc5, counter);

  mlp_fused<true, false><<<NBLK_MLP, 256, 0, stream>>>(
      p0, q0, p1, q1, (const uint4*)frag,
      encW1, encb1, encb2, encW3, encb3,
      P0, Q0, P1, Q1,
      nullptr, nullptr, nullptr, nullptr, nullptr, nullptr, nullptr, nullptr,
      nullptr, nullptr, nullptr, nullptr, n);

  mlp_fused<false, true><<<NBLK_MLP, 256, 0, stream>>>(
      P0, Q0, nullptr, nullptr, (const uint4*)(frag + 8192),
      decW1, decb1, decb2, decW3, decb3,
      nullptr, nullptr, nullptr, nullptr,
      p0, q0, P1, Q1, omega, Pt, Qt, dtp,
      acc5, counter, PQ, (float*)d_out, n);
}

// Round 4
// 293.168 us; speedup vs baseline: 1.6441x; 1.2275x over previous
//
#include <hip/hip_runtime.h>
#include <stdint.h>
#include <math.h>

// PendulumHJBLoss: 3 MLP passes (2->128->128->2, tanh) over N=524288 + losses.
// R4: block=512 (LDS/block ~66KB -> 2 blocks/CU -> 16 waves/CU vs 8 before),
// loss loads hoisted to loop top (latency hidden under tile body),
// block-uniform dual split. Wave-private h1 staging, no in-loop barriers.
// Symplectic FD term exact fp32 (EPS=1e-4 cannot survive bf16).

constexpr float EPS_FD = 1e-4f;
constexpr int NBLK_MLP = 512;     // blocks of 512 threads (8 waves)

typedef float f32x4 __attribute__((ext_vector_type(4)));
typedef short s16x8 __attribute__((ext_vector_type(8)));

__device__ __forceinline__ float tanh_fast(float x) {
  // tanh(x) = 1 - 2/(e^{2x}+1); exp2/rcp single HW instrs.
  float e = __builtin_amdgcn_exp2f(x * 2.8853900817779268f); // 2*log2(e)
  return 1.0f - 2.0f * __builtin_amdgcn_rcpf(e + 1.0f);
}
__device__ __forceinline__ float cos_fast(float x) {
  return __builtin_amdgcn_cosf(x * 0.15915494309189535f);
}
__device__ __forceinline__ unsigned bf16rne(float f) {
  union { float f; unsigned u; } v; v.f = f;
  return (v.u + 0x7FFFu + ((v.u >> 16) & 1u)) >> 16;
}
__device__ __forceinline__ unsigned pack2rne(float a, float b) {
  return bf16rne(a) | (bf16rne(b) << 16);
}
// pack two fp32 -> bf16 pair (round-half-up) with one v_perm
__device__ __forceinline__ unsigned packbf(float lo, float hi) {
  union { float f; unsigned u; } a, b; a.f = lo; b.f = hi;
  return __builtin_amdgcn_perm(b.u + 0x8000u, a.u + 0x8000u, 0x07060302u);
}

// ---------------------------------------------------------------------------
// Setup: blocks 0-63 swizzle W2 -> MFMA B-frags (bf16); blocks 64-127 compute
// the 128 perturbed symplectic encodes in exact fp32 (2 rows per block).
// Block 0 zero-inits loss accumulators + ticket counter.
// ---------------------------------------------------------------------------
__global__ void setup_kernel(const float* __restrict__ encW2,
                             const float* __restrict__ decW2,
                             unsigned* __restrict__ frag,
                             const float* __restrict__ p0, const float* __restrict__ q0,
                             const float* __restrict__ W1, const float* __restrict__ b1,
                             const float* __restrict__ W2, const float* __restrict__ b2,
                             const float* __restrict__ W3, const float* __restrict__ b3,
                             float* __restrict__ PQ,
                             float* __restrict__ acc5, unsigned* __restrict__ counter)
{
  int tid = threadIdx.x;
  if (blockIdx.x < 64) {
    if (blockIdx.x == 0 && tid < 6) {
      if (tid < 5) acc5[tid] = 0.f; else *counter = 0u;
    }
    // W2 swizzle: frag f=s*8+t; lane L holds B[k=32s+(L>>4)*8+j][col=16t+(L&15)]
    int id = blockIdx.x * 256 + tid;            // 0..16383
    const float* W = (id < 8192) ? encW2 : decW2;
    int l = id & 8191;
    int jj   = l & 3;
    int lane = (l >> 2) & 63;
    int f    = l >> 8;
    int s = f >> 3, t = f & 7;
    int quad = lane >> 4, nn = lane & 15;
    int k   = 32 * s + quad * 8 + 2 * jj;
    int col = 16 * t + nn;
    frag[id] = pack2rne(W[k * 128 + col], W[(k + 1) * 128 + col]);
  } else {
    // symplectic rows: row = (blk-64)*2 + (tid>>7); c: 0=p+e 1=p-e 2=q+e 3=q-e
    int half = tid >> 7;
    int tt   = tid & 127;
    int row  = (blockIdx.x - 64) * 2 + half;
    int m = row & 31, c = row >> 5;
    float p = p0[m], q = q0[m];
    if (c == 0) p += EPS_FD; else if (c == 1) p -= EPS_FD;
    else if (c == 2) q += EPS_FD; else q -= EPS_FD;

    __shared__ float h1[2][128];
    h1[half][tt] = tanhf(fmaf(p, W1[tt], fmaf(q, W1[128 + tt], b1[tt])));
    __syncthreads();
    float a = b2[tt];
    for (int k = 0; k < 128; k++) a = fmaf(h1[half][k], W2[k * 128 + tt], a);
    float hh = tanhf(a);
    float cP = hh * W3[2 * tt];
    float cQ = hh * W3[2 * tt + 1];
#pragma unroll
    for (int mm = 1; mm < 64; mm <<= 1) {
      cP += __shfl_xor(cP, mm, 64);
      cQ += __shfl_xor(cQ, mm, 64);
    }
    __shared__ float rr[4][2];
    int wv = tid >> 6, ln = tid & 63;
    if (ln == 0) { rr[wv][0] = cP; rr[wv][1] = cQ; }
    __syncthreads();
    if (tt == 0) {
      PQ[2 * row]     = rr[2 * half][0] + rr[2 * half + 1][0] + b3[0];
      PQ[2 * row + 1] = rr[2 * half][1] + rr[2 * half + 1][1] + b3[1];
    }
  }
}

// ---------------------------------------------------------------------------
// MLP pass, 512 threads (8 waves). DUAL: first half of grid does A, second B.
// LOSS: loss terms fused, loads hoisted to loop top; last block finalizes.
// ---------------------------------------------------------------------------
template<bool DUAL, bool LOSS>
__global__ __launch_bounds__(512, 4) void mlp_fused(
    const float* __restrict__ xpA, const float* __restrict__ xqA,
    const float* __restrict__ xpB, const float* __restrict__ xqB,
    const uint4* __restrict__ w2frag,
    const float* __restrict__ W1, const float* __restrict__ b1,
    const float* __restrict__ b2, const float* __restrict__ W3,
    const float* __restrict__ b3,
    float* __restrict__ oPA, float* __restrict__ oQA,
    float* __restrict__ oPB, float* __restrict__ oQB,
    const float* __restrict__ lp0, const float* __restrict__ lq0,
    const float* __restrict__ lP1, const float* __restrict__ lQ1,
    const float* __restrict__ lom, const float* __restrict__ lPt,
    const float* __restrict__ lQt, const float* __restrict__ ldt,
    float* __restrict__ acc5, unsigned* __restrict__ counter,
    const float* __restrict__ PQ, float* __restrict__ out, int n)
{
  __shared__ uint4 Bf[2048];                 // 32 KB: all 32 B-frags
  __shared__ unsigned h1s[8][16 * 68 + 4];   // wave-private h1 staging
  __shared__ float red[8][5];
  __shared__ unsigned lastflag;

  int tid = threadIdx.x;
  for (int i = tid; i < 2048; i += 512) Bf[i] = w2frag[i];

  int wave = tid >> 6, lane = tid & 63;
  int quad = lane >> 4, l15 = lane & 15;

  // layer-1 consts: lane owns hidden dims 2*lane, 2*lane+1
  float w10_0 = W1[2 * lane],       w10_1 = W1[2 * lane + 1];
  float w11_0 = W1[128 + 2 * lane], w11_1 = W1[128 + 2 * lane + 1];
  float b1_0 = b1[2 * lane], b1_1 = b1[2 * lane + 1];
  float b2v[8], w3P[8], w3Q[8];
#pragma unroll
  for (int t = 0; t < 8; t++) {
    b2v[t] = b2[16 * t + l15];
    w3P[t] = W3[(16 * t + l15) * 2];
    w3Q[t] = W3[(16 * t + l15) * 2 + 1];
  }
  float b3P = b3[0], b3Q = b3[1];
  float dt = 0.f;
  if constexpr (LOSS) dt = ldt[0];
  float s0 = 0.f, s1 = 0.f, s2 = 0.f, s3 = 0.f, s4 = 0.f;
  __syncthreads();   // Bf ready; the ONLY barrier before the tail

  // block-uniform input/output selection
  const float* xp; const float* xq; float* oP; float* oQ;
  int gwave, nwaves;
  if constexpr (DUAL) {
    int halfg = gridDim.x >> 1;
    bool second = blockIdx.x >= halfg;
    xp = second ? xpB : xpA;  xq = second ? xqB : xqA;
    oP = second ? oPB : oPA;  oQ = second ? oQB : oQA;
    gwave  = (blockIdx.x - (second ? halfg : 0)) * 8 + wave;
    nwaves = halfg * 8;
  } else {
    xp = xpA; xq = xqA; oP = oPA; oQ = oQA;
    gwave  = blockIdx.x * 8 + wave;
    nwaves = gridDim.x * 8;
  }
  int ntiles = (n + 15) >> 4;
  unsigned* hrow = &h1s[wave][0];

  for (int tile = gwave; tile < ntiles; tile += nwaves) {
    int base = tile * 16;
    int e = base + l15; if (e >= n) e = n - 1;
    float pe = xp[e], qe = xq[e];

    // hoisted loss loads (broadcast across quads); consumed at loop end
    float Lp0, Lq0, LP0, LQ0, LP1, LQ1, Lom, LPt, LQt;
    int o16;
    if constexpr (LOSS) {
      o16 = base + quad * 4 + (l15 & 3);
      if (o16 >= n) o16 = n - 1;
      Lp0 = lp0[o16]; Lq0 = lq0[o16];
      LP0 = xpA[o16]; LQ0 = xqA[o16];
      LP1 = lP1[o16]; LQ1 = lQ1[o16];
      Lom = lom[o16]; LPt = lPt[o16]; LQt = lQt[o16];
    }

    // layer 1: lane computes h1[e][2*lane..2*lane+1] for e=0..15
#pragma unroll
    for (int ee = 0; ee < 16; ee++) {
      float p = __shfl(pe, ee, 64);
      float q = __shfl(qe, ee, 64);
      float a0 = tanh_fast(fmaf(p, w10_0, fmaf(q, w11_0, b1_0)));
      float a1 = tanh_fast(fmaf(p, w10_1, fmaf(q, w11_1, b1_1)));
      hrow[ee * 68 + lane] = packbf(a0, a1);
    }
    __builtin_amdgcn_wave_barrier();  // same-wave LDS ops are in-order

    // A-frags: lane holds h1[elem=l15][k=32s+quad*8+j]
    s16x8 A[4];
#pragma unroll
    for (int s = 0; s < 4; s++) {
      uint4 u = *reinterpret_cast<const uint4*>(&hrow[l15 * 68 + 16 * s + 4 * quad]);
      A[s] = *reinterpret_cast<s16x8*>(&u);
    }
    __builtin_amdgcn_wave_barrier();  // reads stay before next iter's writes

    f32x4 acc[8];
#pragma unroll
    for (int t = 0; t < 8; t++) {
      f32x4 z = {b2v[t], b2v[t], b2v[t], b2v[t]};   // b2 folded into acc
      acc[t] = z;
    }
#pragma unroll
    for (int s = 0; s < 4; s++) {
#pragma unroll
      for (int t = 0; t < 8; t++) {
        uint4 bu = Bf[(s * 8 + t) * 64 + lane];
        s16x8 Bv = *reinterpret_cast<s16x8*>(&bu);
        acc[t] = __builtin_amdgcn_mfma_f32_16x16x32_bf16(A[s], Bv, acc[t], 0, 0, 0);
      }
    }

    // epilogue: acc[t][r] = h2 pre-act of elem (quad*4+r), col (16t+l15)
    float sP[4] = {0, 0, 0, 0}, sQ[4] = {0, 0, 0, 0};
#pragma unroll
    for (int t = 0; t < 8; t++) {
#pragma unroll
      for (int r = 0; r < 4; r++) {
        float h = tanh_fast(acc[t][r]);
        sP[r] = fmaf(h, w3P[t], sP[r]);
        sQ[r] = fmaf(h, w3Q[t], sQ[r]);
      }
    }
#pragma unroll
    for (int m = 1; m < 16; m <<= 1) {
#pragma unroll
      for (int r = 0; r < 4; r++) {
        sP[r] += __shfl_xor(sP[r], m, 64);
        sQ[r] += __shfl_xor(sQ[r], m, 64);
      }
    }
    if (l15 < 4) {
      float vP = (l15 == 0) ? sP[0] : (l15 == 1) ? sP[1] : (l15 == 2) ? sP[2] : sP[3];
      float vQ = (l15 == 0) ? sQ[0] : (l15 == 1) ? sQ[1] : (l15 == 2) ? sQ[2] : sQ[3];
      vP += b3P; vQ += b3Q;
      int o = base + quad * 4 + l15;
      if (o < n) {
        if constexpr (!LOSS) {
          oP[o] = vP; oQ[o] = vQ;
        } else {
          // vP,vQ = p0_recon,q0_recon at element o == o16
          float dp = Lp0 - vP, dq = Lq0 - vQ;
          s0 += dp * dp + dq * dq;
          float d1 = LP0 - LP1; s1 += d1 * d1;
          s2 += 1.0f - cos_fast(LQ1 - LQ0 - Lom * dt);
          float g = LP0 - LPt; s3 += g * g;
          s4 += 1.0f - cos_fast(LQ0 - LQt);
        }
      }
    }
  }

  if constexpr (LOSS) {
#pragma unroll
    for (int m = 1; m < 64; m <<= 1) {
      s0 += __shfl_xor(s0, m, 64);
      s1 += __shfl_xor(s1, m, 64);
      s2 += __shfl_xor(s2, m, 64);
      s3 += __shfl_xor(s3, m, 64);
      s4 += __shfl_xor(s4, m, 64);
    }
    if (lane == 0) {
      red[wave][0] = s0; red[wave][1] = s1; red[wave][2] = s2;
      red[wave][3] = s3; red[wave][4] = s4;
    }
    __syncthreads();
    if (tid == 0) {
#pragma unroll
      for (int i = 0; i < 5; i++) {
        float v = 0.f;
#pragma unroll
        for (int w = 0; w < 8; w++) v += red[w][i];
        atomicAdd(&acc5[i], v);
      }
      __threadfence();
      unsigned prev = atomicAdd(counter, 1u);
      lastflag = (prev == gridDim.x - 1) ? 1u : 0u;
    }
    __syncthreads();
    if (lastflag) {
      __threadfence();
      if (tid < 64) {
        float v = 0.f;
        if (tid < 32) {
          float Ppp = PQ[2 * tid],          Qpp = PQ[2 * tid + 1];
          float Ppm = PQ[2 * (32 + tid)],   Qpm = PQ[2 * (32 + tid) + 1];
          float Pqp = PQ[2 * (64 + tid)],   Qqp = PQ[2 * (64 + tid) + 1];
          float Pqm = PQ[2 * (96 + tid)],   Qqm = PQ[2 * (96 + tid) + 1];
          float inv2e = 1.0f / (2.0f * EPS_FD);
          float dPdp = (Ppp - Ppm) * inv2e, dPdq = (Pqp - Pqm) * inv2e;
          float dQdp = (Qpp - Qpm) * inv2e, dQdq = (Qqp - Qqm) * inv2e;
          float pb = dPdq * dQdp - dPdp * dQdq;
          float d = fabsf(pb) - 1.0f;
          v = d * d;
        }
#pragma unroll
        for (int m = 1; m < 64; m <<= 1) v += __shfl_xor(v, m, 64);
        if (tid == 0) {
          float inv_n = 1.0f / (float)n;
          float recon = atomicAdd(&acc5[0], 0.f) * inv_n;
          float cons  = atomicAdd(&acc5[1], 0.f) * inv_n;
          float evo   = atomicAdd(&acc5[2], 0.f) * inv_n;
          float gauge = (atomicAdd(&acc5[3], 0.f) + atomicAdd(&acc5[4], 0.f)) * inv_n;
          float symp  = v * (1.0f / 32.0f);
          float total = recon + 10.0f * cons + 5.0f * evo + 0.1f * symp + 5.0f * gauge;
          out[0] = total; out[1] = recon; out[2] = cons;
          out[3] = evo;   out[4] = symp;  out[5] = gauge;
        }
      }
    }
  }
}

extern "C" void kernel_launch(void* const* d_in, const int* in_sizes, int n_in,
                              void* d_out, int out_size, void* d_ws, size_t ws_size,
                              hipStream_t stream)
{
  const float* p0    = (const float*)d_in[0];
  const float* q0    = (const float*)d_in[1];
  const float* p1    = (const float*)d_in[2];
  const float* q1    = (const float*)d_in[3];
  const float* omega = (const float*)d_in[4];
  const float* dtp   = (const float*)d_in[5];
  const float* Pt    = (const float*)d_in[6];
  const float* Qt    = (const float*)d_in[7];
  const float* encW1 = (const float*)d_in[8];
  const float* encb1 = (const float*)d_in[9];
  const float* encW2 = (const float*)d_in[10];
  const float* encb2 = (const float*)d_in[11];
  const float* encW3 = (const float*)d_in[12];
  const float* encb3 = (const float*)d_in[13];
  const float* decW1 = (const float*)d_in[14];
  const float* decb1 = (const float*)d_in[15];
  const float* decW2 = (const float*)d_in[16];
  const float* decb2 = (const float*)d_in[17];
  const float* decW3 = (const float*)d_in[18];
  const float* decb3 = (const float*)d_in[19];

  int n = in_sizes[0];
  char* ws = (char*)d_ws;
  unsigned* frag = (unsigned*)ws;              // 16384 u32 = 64 KB
  float* P0 = (float*)(ws + 65536);
  float* Q0 = P0 + n;
  float* P1 = Q0 + n;
  float* Q1 = P1 + n;
  float* PQ = Q1 + n;                          // 256 floats
  float* acc5 = PQ + 256;                      // 5 accumulators
  unsigned* counter = (unsigned*)(acc5 + 8);   // ticket

  setup_kernel<<<128, 256, 0, stream>>>(encW2, decW2, frag,
                                        p0, q0, encW1, encb1, encW2, encb2,
                                        encW3, encb3, PQ, acc5, counter);

  mlp_fused<true, false><<<NBLK_MLP, 512, 0, stream>>>(
      p0, q0, p1, q1, (const uint4*)frag,
      encW1, encb1, encb2, encW3, encb3,
      P0, Q0, P1, Q1,
      nullptr, nullptr, nullptr, nullptr, nullptr, nullptr, nullptr, nullptr,
      nullptr, nullptr, nullptr, nullptr, n);

  mlp_fused<false, true><<<NBLK_MLP, 512, 0, stream>>>(
      P0, Q0, nullptr, nullptr, (const uint4*)(frag + 8192),
      decW1, decb1, decb2, decW3, decb3,
      nullptr, nullptr, nullptr, nullptr,
      p0, q0, P1, Q1, omega, Pt, Qt, dtp,
      acc5, counter, PQ, (float*)d_out, n);
}

// Round 5
// 292.997 us; speedup vs baseline: 1.6450x; 1.0006x over previous
//
#include <hip/hip_runtime.h>
#include <stdint.h>
#include <math.h>

// PendulumHJBLoss: 3 MLP passes (2->128->128->2, tanh) over N=524288 + losses.
// R5: ONE persistent kernel does enc(p0,q0)+enc(p1,q1)+dec in-register per
// tile (no intermediate global arrays, no 2nd dispatch). 1024-thr blocks,
// both B-frag sets resident in LDS (64 KB), wave-private h1 staging, no
// in-loop barriers. Dec epilogue consts from LDS to stay <=128 VGPR.
// Symplectic FD term exact fp32 in setup kernel (EPS=1e-4 vs bf16).

constexpr float EPS_FD = 1e-4f;
constexpr int NBLK = 256;          // 1 block/CU, 16 waves each

typedef float f32x4 __attribute__((ext_vector_type(4)));
typedef short s16x8 __attribute__((ext_vector_type(8)));

__device__ __forceinline__ float tanh_fast(float x) {
  float e = __builtin_amdgcn_exp2f(x * 2.8853900817779268f); // 2*log2(e)
  return 1.0f - 2.0f * __builtin_amdgcn_rcpf(e + 1.0f);
}
__device__ __forceinline__ float cos_fast(float x) {
  return __builtin_amdgcn_cosf(x * 0.15915494309189535f);
}
__device__ __forceinline__ unsigned bf16rne(float f) {
  union { float f; unsigned u; } v; v.f = f;
  return (v.u + 0x7FFFu + ((v.u >> 16) & 1u)) >> 16;
}
__device__ __forceinline__ unsigned pack2rne(float a, float b) {
  return bf16rne(a) | (bf16rne(b) << 16);
}
// two fp32 -> packed bf16 pair (round-half-up) with one v_perm
__device__ __forceinline__ unsigned packbf(float lo, float hi) {
  union { float f; unsigned u; } a, b; a.f = lo; b.f = hi;
  return __builtin_amdgcn_perm(b.u + 0x8000u, a.u + 0x8000u, 0x07060302u);
}

// ---------------------------------------------------------------------------
// Setup: blocks 0-63 swizzle W2 -> MFMA B-frags (bf16); blocks 64-127 compute
// the 128 perturbed symplectic encodes in exact fp32 (2 rows per block).
// Block 0 zero-inits loss accumulators + ticket counter.
// ---------------------------------------------------------------------------
__global__ void setup_kernel(const float* __restrict__ encW2,
                             const float* __restrict__ decW2,
                             unsigned* __restrict__ frag,
                             const float* __restrict__ p0, const float* __restrict__ q0,
                             const float* __restrict__ W1, const float* __restrict__ b1,
                             const float* __restrict__ W2, const float* __restrict__ b2,
                             const float* __restrict__ W3, const float* __restrict__ b3,
                             float* __restrict__ PQ,
                             float* __restrict__ acc5, unsigned* __restrict__ counter)
{
  int tid = threadIdx.x;
  if (blockIdx.x < 64) {
    if (blockIdx.x == 0 && tid < 6) {
      if (tid < 5) acc5[tid] = 0.f; else *counter = 0u;
    }
    // frag f=s*8+t; lane L holds B[k=32s+(L>>4)*8+j][col=16t+(L&15)]
    int id = blockIdx.x * 256 + tid;            // 0..16383
    const float* W = (id < 8192) ? encW2 : decW2;
    int l = id & 8191;
    int jj   = l & 3;
    int lane = (l >> 2) & 63;
    int f    = l >> 8;
    int s = f >> 3, t = f & 7;
    int quad = lane >> 4, nn = lane & 15;
    int k   = 32 * s + quad * 8 + 2 * jj;
    int col = 16 * t + nn;
    frag[id] = pack2rne(W[k * 128 + col], W[(k + 1) * 128 + col]);
  } else {
    int half = tid >> 7;
    int tt   = tid & 127;
    int row  = (blockIdx.x - 64) * 2 + half;
    int m = row & 31, c = row >> 5;   // c: 0=p+e 1=p-e 2=q+e 3=q-e
    float p = p0[m], q = q0[m];
    if (c == 0) p += EPS_FD; else if (c == 1) p -= EPS_FD;
    else if (c == 2) q += EPS_FD; else q -= EPS_FD;

    __shared__ float h1[2][128];
    h1[half][tt] = tanhf(fmaf(p, W1[tt], fmaf(q, W1[128 + tt], b1[tt])));
    __syncthreads();
    float a = b2[tt];
    for (int k = 0; k < 128; k++) a = fmaf(h1[half][k], W2[k * 128 + tt], a);
    float hh = tanhf(a);
    float cP = hh * W3[2 * tt];
    float cQ = hh * W3[2 * tt + 1];
#pragma unroll
    for (int mm = 1; mm < 64; mm <<= 1) {
      cP += __shfl_xor(cP, mm, 64);
      cQ += __shfl_xor(cQ, mm, 64);
    }
    __shared__ float rr[4][2];
    int wv = tid >> 6, ln = tid & 63;
    if (ln == 0) { rr[wv][0] = cP; rr[wv][1] = cQ; }
    __syncthreads();
    if (tt == 0) {
      PQ[2 * row]     = rr[2 * half][0] + rr[2 * half + 1][0] + b3[0];
      PQ[2 * row + 1] = rr[2 * half][1] + rr[2 * half + 1][1] + b3[1];
    }
  }
}

// ---------------------------------------------------------------------------
// One MLP pass for a 16-elem tile held per-wave.
// SCAT: layer-1 input lives on scattered owner lanes (16*(ee>>2)+(ee&3))
//       instead of lanes 0..15 (used for the dec pass fed by enc outputs).
// EPI_LDS: epilogue consts (b2, W3) read from LDS array epi[384] instead of
//          register arrays (saves 24 VGPRs for the dec pass).
// Outputs vP,vQ valid on lanes with l15<4: element = base + quad*4 + l15.
// ---------------------------------------------------------------------------
template<bool SCAT, bool EPI_LDS>
__device__ __forceinline__ void mlp_pass(
    float pe, float qe, unsigned* hrow, const uint4* Bf,
    float w100, float w101, float w110, float w111, float b10, float b11,
    const float (&rb2)[8], const float (&rw3P)[8], const float (&rw3Q)[8],
    const float* epi,
    int lane, int quad, int l15, float b3P, float b3Q,
    float& vP, float& vQ)
{
  // layer 1: lane computes h1[ee][2*lane..2*lane+1] for ee=0..15
#pragma unroll
  for (int ee = 0; ee < 16; ee++) {
    int src = SCAT ? (16 * (ee >> 2) + (ee & 3)) : ee;
    float p = __shfl(pe, src, 64);
    float q = __shfl(qe, src, 64);
    float a0 = tanh_fast(fmaf(p, w100, fmaf(q, w110, b10)));
    float a1 = tanh_fast(fmaf(p, w101, fmaf(q, w111, b11)));
    hrow[ee * 68 + lane] = packbf(a0, a1);
  }
  __builtin_amdgcn_wave_barrier();   // same-wave LDS ops are in-order

  // A-frags: lane holds h1[elem=l15][k=32s+quad*8+j]
  s16x8 A[4];
#pragma unroll
  for (int s = 0; s < 4; s++) {
    uint4 u = *reinterpret_cast<const uint4*>(&hrow[l15 * 68 + 16 * s + 4 * quad]);
    A[s] = *reinterpret_cast<s16x8*>(&u);
  }
  __builtin_amdgcn_wave_barrier();   // reads stay before next pass's writes

  float b2v[8];
#pragma unroll
  for (int t = 0; t < 8; t++) b2v[t] = EPI_LDS ? epi[16 * t + l15] : rb2[t];

  f32x4 acc[8];
#pragma unroll
  for (int t = 0; t < 8; t++) {
    f32x4 z = {b2v[t], b2v[t], b2v[t], b2v[t]};
    acc[t] = z;
  }
#pragma unroll
  for (int s = 0; s < 4; s++) {
#pragma unroll
    for (int t = 0; t < 8; t++) {
      uint4 bu = Bf[(s * 8 + t) * 64 + lane];
      s16x8 Bv = *reinterpret_cast<s16x8*>(&bu);
      acc[t] = __builtin_amdgcn_mfma_f32_16x16x32_bf16(A[s], Bv, acc[t], 0, 0, 0);
    }
  }

  float w3Pv[8], w3Qv[8];
#pragma unroll
  for (int t = 0; t < 8; t++) {
    w3Pv[t] = EPI_LDS ? epi[128 + 16 * t + l15] : rw3P[t];
    w3Qv[t] = EPI_LDS ? epi[256 + 16 * t + l15] : rw3Q[t];
  }

  // epilogue: acc[t][r] = h2 pre-act of elem (quad*4+r), col (16t+l15)
  float sP[4] = {0, 0, 0, 0}, sQ[4] = {0, 0, 0, 0};
#pragma unroll
  for (int t = 0; t < 8; t++) {
#pragma unroll
    for (int r = 0; r < 4; r++) {
      float h = tanh_fast(acc[t][r]);
      sP[r] = fmaf(h, w3Pv[t], sP[r]);
      sQ[r] = fmaf(h, w3Qv[t], sQ[r]);
    }
  }
#pragma unroll
  for (int m = 1; m < 16; m <<= 1) {
#pragma unroll
    for (int r = 0; r < 4; r++) {
      sP[r] += __shfl_xor(sP[r], m, 64);
      sQ[r] += __shfl_xor(sQ[r], m, 64);
    }
  }
  vP = ((l15 == 0) ? sP[0] : (l15 == 1) ? sP[1] : (l15 == 2) ? sP[2] : sP[3]) + b3P;
  vQ = ((l15 == 0) ? sQ[0] : (l15 == 1) ? sQ[1] : (l15 == 2) ? sQ[2] : sQ[3]) + b3Q;
}

// ---------------------------------------------------------------------------
// Persistent merged kernel: per tile enc(p0,q0), enc(p1,q1), dec -> losses.
// Last finishing block computes d_out[6].
// ---------------------------------------------------------------------------
__global__ __launch_bounds__(1024, 4) void mlp_all(
    const float* __restrict__ p0, const float* __restrict__ q0,
    const float* __restrict__ p1, const float* __restrict__ q1,
    const uint4* __restrict__ w2frag,
    const float* __restrict__ eW1, const float* __restrict__ eb1,
    const float* __restrict__ eb2, const float* __restrict__ eW3,
    const float* __restrict__ eb3,
    const float* __restrict__ dW1, const float* __restrict__ db1,
    const float* __restrict__ db2, const float* __restrict__ dW3,
    const float* __restrict__ db3,
    const float* __restrict__ omega, const float* __restrict__ Pt,
    const float* __restrict__ Qt, const float* __restrict__ dtp,
    float* __restrict__ acc5, unsigned* __restrict__ counter,
    const float* __restrict__ PQ, float* __restrict__ out, int n)
{
  __shared__ uint4 BfE[2048];               // 32 KB enc B-frags
  __shared__ uint4 BfD[2048];               // 32 KB dec B-frags
  __shared__ unsigned h1s[16][16 * 68 + 4]; // wave-private h1 staging (~70 KB)
  __shared__ float decEpi[384];             // dec b2 | W3P | W3Q
  __shared__ float red[16][5];
  __shared__ unsigned lastflag;

  int tid = threadIdx.x;
  for (int i = tid; i < 2048; i += 1024) {
    BfE[i] = w2frag[i];
    BfD[i] = w2frag[2048 + i];
  }
  if (tid < 128) {
    decEpi[tid]       = db2[tid];
    decEpi[128 + tid] = dW3[2 * tid];
    decEpi[256 + tid] = dW3[2 * tid + 1];
  }

  int wave = tid >> 6, lane = tid & 63;
  int quad = lane >> 4, l15 = lane & 15;

  // enc + dec layer-1 consts (lane owns hidden dims 2*lane, 2*lane+1)
  float ew100 = eW1[2 * lane],       ew101 = eW1[2 * lane + 1];
  float ew110 = eW1[128 + 2 * lane], ew111 = eW1[128 + 2 * lane + 1];
  float eb10 = eb1[2 * lane], eb11 = eb1[2 * lane + 1];
  float dw100 = dW1[2 * lane],       dw101 = dW1[2 * lane + 1];
  float dw110 = dW1[128 + 2 * lane], dw111 = dW1[128 + 2 * lane + 1];
  float db10 = db1[2 * lane], db11 = db1[2 * lane + 1];
  // enc epilogue consts in registers (used twice per tile)
  float eb2v[8], ew3P[8], ew3Q[8];
#pragma unroll
  for (int t = 0; t < 8; t++) {
    eb2v[t] = eb2[16 * t + l15];
    ew3P[t] = eW3[(16 * t + l15) * 2];
    ew3Q[t] = eW3[(16 * t + l15) * 2 + 1];
  }
  float eb3P = eb3[0], eb3Q = eb3[1];
  float db3P = db3[0], db3Q = db3[1];
  float dt = dtp[0];
  float s0 = 0.f, s1 = 0.f, s2 = 0.f, s3 = 0.f, s4 = 0.f;
  __syncthreads();   // Bf/decEpi ready; the only barrier before the tail

  int nwaves = gridDim.x * 16;
  int gwave  = blockIdx.x * 16 + wave;
  int ntiles = (n + 15) >> 4;
  unsigned* hrow = &h1s[wave][0];

  for (int tile = gwave; tile < ntiles; tile += nwaves) {
    int base = tile * 16;
    int e = base + l15; if (e >= n) e = n - 1;
    float p0e = p0[e], q0e = q0[e];
    float p1e = p1[e], q1e = q1[e];
    // hoisted loss loads at the scattered output index
    int o = base + quad * 4 + l15;                 // valid where l15<4
    int o16 = base + quad * 4 + (l15 & 3);
    if (o16 >= n) o16 = n - 1;
    float Lom = omega[o16], LPt = Pt[o16], LQt = Qt[o16];
    float Lp0 = p0[o16],    Lq0 = q0[o16];

    float P0v, Q0v, P1v, Q1v, RPv, RQv;
    mlp_pass<false, false>(p0e, q0e, hrow, BfE,
                           ew100, ew101, ew110, ew111, eb10, eb11,
                           eb2v, ew3P, ew3Q, decEpi,
                           lane, quad, l15, eb3P, eb3Q, P0v, Q0v);
    mlp_pass<false, false>(p1e, q1e, hrow, BfE,
                           ew100, ew101, ew110, ew111, eb10, eb11,
                           eb2v, ew3P, ew3Q, decEpi,
                           lane, quad, l15, eb3P, eb3Q, P1v, Q1v);
    // dec input: enc outputs on scattered owner lanes (16*(ee>>2)+(ee&3))
    mlp_pass<true, true>(P0v, Q0v, hrow, BfD,
                         dw100, dw101, dw110, dw111, db10, db11,
                         eb2v, ew3P, ew3Q, decEpi,
                         lane, quad, l15, db3P, db3Q, RPv, RQv);

    if (l15 < 4 && o < n) {
      float dp = Lp0 - RPv, dq = Lq0 - RQv;
      s0 += dp * dp + dq * dq;                       // recon
      float d1 = P0v - P1v; s1 += d1 * d1;           // conservation
      s2 += 1.0f - cos_fast(Q1v - Q0v - Lom * dt);   // evolution
      float g = P0v - LPt; s3 += g * g;              // gauge P
      s4 += 1.0f - cos_fast(Q0v - LQt);              // gauge Q
    }
  }

  // block reduction -> global accumulators -> ticket -> last block finalizes
#pragma unroll
  for (int m = 1; m < 64; m <<= 1) {
    s0 += __shfl_xor(s0, m, 64);
    s1 += __shfl_xor(s1, m, 64);
    s2 += __shfl_xor(s2, m, 64);
    s3 += __shfl_xor(s3, m, 64);
    s4 += __shfl_xor(s4, m, 64);
  }
  if (lane == 0) {
    red[wave][0] = s0; red[wave][1] = s1; red[wave][2] = s2;
    red[wave][3] = s3; red[wave][4] = s4;
  }
  __syncthreads();
  if (tid == 0) {
#pragma unroll
    for (int i = 0; i < 5; i++) {
      float v = 0.f;
#pragma unroll
      for (int w = 0; w < 16; w++) v += red[w][i];
      atomicAdd(&acc5[i], v);
    }
    __threadfence();
    unsigned prev = atomicAdd(counter, 1u);
    lastflag = (prev == gridDim.x - 1) ? 1u : 0u;
  }
  __syncthreads();
  if (lastflag) {
    __threadfence();
    if (tid < 64) {
      float v = 0.f;
      if (tid < 32) {
        float Ppp = PQ[2 * tid],          Qpp = PQ[2 * tid + 1];
        float Ppm = PQ[2 * (32 + tid)],   Qpm = PQ[2 * (32 + tid) + 1];
        float Pqp = PQ[2 * (64 + tid)],   Qqp = PQ[2 * (64 + tid) + 1];
        float Pqm = PQ[2 * (96 + tid)],   Qqm = PQ[2 * (96 + tid) + 1];
        float inv2e = 1.0f / (2.0f * EPS_FD);
        float dPdp = (Ppp - Ppm) * inv2e, dPdq = (Pqp - Pqm) * inv2e;
        float dQdp = (Qpp - Qpm) * inv2e, dQdq = (Qqp - Qqm) * inv2e;
        float pb = dPdq * dQdp - dPdp * dQdq;
        float d = fabsf(pb) - 1.0f;
        v = d * d;
      }
#pragma unroll
      for (int m = 1; m < 64; m <<= 1) v += __shfl_xor(v, m, 64);
      if (tid == 0) {
        float inv_n = 1.0f / (float)n;
        float recon = atomicAdd(&acc5[0], 0.f) * inv_n;
        float cons  = atomicAdd(&acc5[1], 0.f) * inv_n;
        float evo   = atomicAdd(&acc5[2], 0.f) * inv_n;
        float gauge = (atomicAdd(&acc5[3], 0.f) + atomicAdd(&acc5[4], 0.f)) * inv_n;
        float symp  = v * (1.0f / 32.0f);
        float total = recon + 10.0f * cons + 5.0f * evo + 0.1f * symp + 5.0f * gauge;
        out[0] = total; out[1] = recon; out[2] = cons;
        out[3] = evo;   out[4] = symp;  out[5] = gauge;
      }
    }
  }
}

extern "C" void kernel_launch(void* const* d_in, const int* in_sizes, int n_in,
                              void* d_out, int out_size, void* d_ws, size_t ws_size,
                              hipStream_t stream)
{
  const float* p0    = (const float*)d_in[0];
  const float* q0    = (const float*)d_in[1];
  const float* p1    = (const float*)d_in[2];
  const float* q1    = (const float*)d_in[3];
  const float* omega = (const float*)d_in[4];
  const float* dtp   = (const float*)d_in[5];
  const float* Pt    = (const float*)d_in[6];
  const float* Qt    = (const float*)d_in[7];
  const float* encW1 = (const float*)d_in[8];
  const float* encb1 = (const float*)d_in[9];
  const float* encW2 = (const float*)d_in[10];
  const float* encb2 = (const float*)d_in[11];
  const float* encW3 = (const float*)d_in[12];
  const float* encb3 = (const float*)d_in[13];
  const float* decW1 = (const float*)d_in[14];
  const float* decb1 = (const float*)d_in[15];
  const float* decW2 = (const float*)d_in[16];
  const float* decb2 = (const float*)d_in[17];
  const float* decW3 = (const float*)d_in[18];
  const float* decb3 = (const float*)d_in[19];

  int n = in_sizes[0];
  char* ws = (char*)d_ws;
  unsigned* frag = (unsigned*)ws;              // 16384 u32 = 64 KB
  float* PQ   = (float*)(ws + 65536);          // 256 floats
  float* acc5 = PQ + 256;                      // 5 accumulators
  unsigned* counter = (unsigned*)(acc5 + 8);   // ticket

  setup_kernel<<<128, 256, 0, stream>>>(encW2, decW2, frag,
                                        p0, q0, encW1, encb1, encW2, encb2,
                                        encW3, encb3, PQ, acc5, counter);

  mlp_all<<<NBLK, 1024, 0, stream>>>(
      p0, q0, p1, q1, (const uint4*)frag,
      encW1, encb1, encb2, encW3, encb3,
      decW1, decb1, decb2, decW3, decb3,
      omega, Pt, Qt, dtp,
      acc5, counter, PQ, (float*)d_out, n);
}